// Round 12
// baseline (168.654 us; speedup 1.0000x reference)
//
#include <hip/hip_runtime.h>

#define Bv 8
#define Cc 256
#define Nn 2304
#define EPS 1e-5f

typedef float f32x4 __attribute__((ext_vector_type(4)));
typedef __bf16 bf16x8 __attribute__((ext_vector_type(8)));

static __device__ __forceinline__ f32x4 mfma16(bf16x8 a, bf16x8 b, f32x4 c) {
    return __builtin_amdgcn_mfma_f32_16x16x32_bf16(a, b, c, 0, 0, 0);
}

static __device__ __forceinline__ bf16x8 cvt8(float4 a, float4 b) {
    bf16x8 r;
    r[0] = (__bf16)a.x; r[1] = (__bf16)a.y; r[2] = (__bf16)a.z; r[3] = (__bf16)a.w;
    r[4] = (__bf16)b.x; r[5] = (__bf16)b.y; r[6] = (__bf16)b.z; r[7] = (__bf16)b.w;
    return r;
}

// load 8 fp32 from four partial slabs, sum, convert
static __device__ __forceinline__ bf16x8 load4_add_cvt8(
    const float* __restrict__ p0, const float* __restrict__ p1,
    const float* __restrict__ p2, const float* __restrict__ p3) {
    float4 x0 = *(const float4*)p0, x1 = *(const float4*)(p0 + 4);
    float4 y0 = *(const float4*)p1, y1 = *(const float4*)(p1 + 4);
    float4 z0 = *(const float4*)p2, z1 = *(const float4*)(p2 + 4);
    float4 w0 = *(const float4*)p3, w1 = *(const float4*)(p3 + 4);
    bf16x8 r;
    r[0] = (__bf16)(x0.x + y0.x + z0.x + w0.x);
    r[1] = (__bf16)(x0.y + y0.y + z0.y + w0.y);
    r[2] = (__bf16)(x0.z + y0.z + z0.z + w0.z);
    r[3] = (__bf16)(x0.w + y0.w + z0.w + w0.w);
    r[4] = (__bf16)(x1.x + y1.x + z1.x + w1.x);
    r[5] = (__bf16)(x1.y + y1.y + z1.y + w1.y);
    r[6] = (__bf16)(x1.z + y1.z + z1.z + w1.z);
    r[7] = (__bf16)(x1.w + y1.w + z1.w + w1.w);
    return r;
}

// ---------------------------------------------------------------------------
// k_front: two independent jobs:
//   blocks [0,512):    Spart[kc][b] = KVf_chunk @ KVf_chunk^T (4-way split-K,
//                      K-chunk 576, K-step 64, 2-phase reg-prefetch pipeline,
//                      plain stores, b->XCD pinned)
//   blocks [512,1024): L = (1/N)*diag(inv)*(Wz@Wv), Rt = Wq^T@Wk  (bf16 out)
// ---------------------------------------------------------------------------
__global__ __launch_bounds__(256) void k_front(
    const float* __restrict__ KVf,
    const float* __restrict__ Wq, const float* __restrict__ Wk,
    const float* __restrict__ Wv, const float* __restrict__ Wz,
    const float* __restrict__ gamma, const float* __restrict__ var_,
    unsigned short* __restrict__ Lb_us, unsigned short* __restrict__ Rtb_us,
    float* __restrict__ Spart) {
    __shared__ __align__(16) char smem[32768];
    int blk = blockIdx.x, tid = threadIdx.x;

    if (blk < 512) {
        // ---- syrk partial: 64x64 tile, K=576 chunk, K-step 64, pipelined ----
        __bf16 (*As)[72] = (__bf16 (*)[72])smem;                 // 64*72*2 = 9216 B
        __bf16 (*Bs)[72] = (__bf16 (*)[72])(smem + 9216);
        int b = blk & 7;                   // b -> XCD pin
        int tt = (blk >> 3) & 15;
        int kc = blk >> 7;                 // 0..3
        int tr = (tt >> 2) * 64, tc = (tt & 3) * 64;
        int k0 = kc * 576;
        int l = tid & 63, w = tid >> 6;
        int lr = l & 15, kofs = (l >> 4) * 8;
        int row = tid >> 2, c0 = (tid & 3) * 16;
        const float* Ap = KVf + ((size_t)b * Cc + tr + row) * Nn + k0 + c0;
        const float* Bp = KVf + ((size_t)b * Cc + tc + row) * Nn + k0 + c0;
        float4 fa0, fa1, fa2, fa3, fb0, fb1, fb2, fb3;
#define LD_TILE(ks) do { \
        const float* ap_ = Ap + (ks) * 64; \
        const float* bp_ = Bp + (ks) * 64; \
        fa0 = *(const float4*)ap_;         fa1 = *(const float4*)(ap_ + 4); \
        fa2 = *(const float4*)(ap_ + 8);   fa3 = *(const float4*)(ap_ + 12); \
        fb0 = *(const float4*)bp_;         fb1 = *(const float4*)(bp_ + 4); \
        fb2 = *(const float4*)(bp_ + 8);   fb3 = *(const float4*)(bp_ + 12); \
    } while (0)
        f32x4 zero = {0.f, 0.f, 0.f, 0.f};
        f32x4 acc[4] = {zero, zero, zero, zero};
        LD_TILE(0);
        for (int ks = 0; ks < 9; ++ks) {
            *(bf16x8*)&As[row][c0]     = cvt8(fa0, fa1);
            *(bf16x8*)&As[row][c0 + 8] = cvt8(fa2, fa3);
            *(bf16x8*)&Bs[row][c0]     = cvt8(fb0, fb1);
            *(bf16x8*)&Bs[row][c0 + 8] = cvt8(fb2, fb3);
            __syncthreads();
            if (ks < 8) LD_TILE(ks + 1);   // prefetch next tile into regs
#pragma unroll
            for (int kk = 0; kk < 64; kk += 32) {
                bf16x8 af = *(const bf16x8*)&As[w * 16 + lr][kk + kofs];
#pragma unroll
                for (int j = 0; j < 4; ++j) {
                    bf16x8 bb = *(const bf16x8*)&Bs[j * 16 + lr][kk + kofs];
                    acc[j] = mfma16(af, bb, acc[j]);
                }
            }
            __syncthreads();
        }
#undef LD_TILE
        float* Sp = Spart + ((size_t)kc * Bv + b) * 65536;
        int row0 = tr + w * 16 + ((l >> 4) << 2);
#pragma unroll
        for (int j = 0; j < 4; ++j) {
            int col = tc + j * 16 + lr;
#pragma unroll
            for (int r = 0; r < 4; ++r)
                Sp[(size_t)(row0 + r) * 256 + col] = acc[j][r];
        }
    } else {
        // ---- weight GEMMs (fp32 LDS dot) ----
        float* bufA = (float*)smem;
        float* bufB = bufA + 4096;
        __bf16* Lb  = (__bf16*)Lb_us;
        __bf16* Rtb = (__bf16*)Rtb_us;
        int wblk = blk - 512;
        bool isL = (wblk < 256);
        int t = isL ? wblk : wblk - 256;
        int tr = (t >> 4) * 16, tc = (t & 15) * 16;
        if (isL) {
            for (int idx = tid; idx < 4096; idx += 256) {
                int r = idx >> 8, m = idx & 255;
                bufA[idx] = Wz[(tr + r) * 256 + m];          // [16][256] rows of Wz
            }
            for (int idx = tid; idx < 4096; idx += 256) {
                int m = idx >> 4, j = idx & 15;
                bufB[idx] = Wv[m * 256 + tc + j];            // [256][16] cols of Wv
            }
        } else {
            for (int idx = tid; idx < 4096; idx += 256) {
                int o = idx >> 4, j = idx & 15;
                bufA[idx] = Wq[o * 256 + tr + j];            // [256][16] cols of Wq
                bufB[idx] = Wk[o * 256 + tc + j];            // [256][16] cols of Wk
            }
        }
        __syncthreads();
        int oo = tid >> 4, cc = tid & 15;
        float sum = 0.f;
        if (isL) {
#pragma unroll 8
            for (int m = 0; m < 256; ++m) sum += bufA[oo * 256 + m] * bufB[m * 16 + cc];
            int o = tr + oo;
            float inv = gamma[o] / sqrtf(var_[o] + EPS);
            Lb[o * 256 + tc + cc] = (__bf16)(inv * sum * (1.0f / (float)Nn));
        } else {
#pragma unroll 8
            for (int o = 0; o < 256; ++o) sum += bufA[o * 16 + oo] * bufB[o * 16 + cc];
            Rtb[(tr + oo) * 256 + tc + cc] = (__bf16)sum;
        }
    }
}

// ---------------------------------------------------------------------------
// k_mid: per 16-row stripe of one batch:
//   T-stripe[16][256] = L[r0:r0+16][:] @ (S0+S1+S2+S3)   (NT via S symmetry)
//   -> LDS (bf16), then P-stripe[16][256] = T-stripe @ R  (NT with Rt)
// grid 128 = 16 stripes x 8 b (b->XCD pin). 4 waves; wave w owns 64 cols.
// ---------------------------------------------------------------------------
__global__ __launch_bounds__(256) void k_mid(
    const unsigned short* __restrict__ Lb_us, const float* __restrict__ Spart,
    const unsigned short* __restrict__ Rtb_us, unsigned short* __restrict__ Pb_us) {
    __shared__ __bf16 Ts[16][264];       // 8448 B, pitch 264 keeps 16B align
    const __bf16* Lb = (const __bf16*)Lb_us;
    const __bf16* Rtb = (const __bf16*)Rtb_us;
    __bf16* Pb = (__bf16*)Pb_us;
    int blk = blockIdx.x;
    int b = blk & 7, st = blk >> 3;      // stripe 0..15
    int r0 = st * 16;
    int tid = threadIdx.x, l = tid & 63, w = tid >> 6;
    int lr = l & 15, kofs = (l >> 4) * 8;
    const float* S0 = Spart + (size_t)(0 * Bv + b) * 65536;
    const float* S1 = Spart + (size_t)(1 * Bv + b) * 65536;
    const float* S2 = Spart + (size_t)(2 * Bv + b) * 65536;
    const float* S3 = Spart + (size_t)(3 * Bv + b) * 65536;
    f32x4 zero = {0.f, 0.f, 0.f, 0.f};

    // GEMM1: T-stripe = L[r0:r0+16][:] @ Ssum  (B-row = Ssum[col][:], S symmetric)
    {
        f32x4 acc[4] = {zero, zero, zero, zero};
        for (int kk = 0; kk < 256; kk += 32) {
            bf16x8 af = *(const bf16x8*)&Lb[(r0 + lr) * 256 + kk + kofs];
#pragma unroll
            for (int j = 0; j < 4; ++j) {
                size_t boff = (size_t)(w * 64 + j * 16 + lr) * 256 + kk + kofs;
                bf16x8 bb = load4_add_cvt8(S0 + boff, S1 + boff, S2 + boff, S3 + boff);
                acc[j] = mfma16(af, bb, acc[j]);
            }
        }
        int rloc = (l >> 4) << 2;
#pragma unroll
        for (int j = 0; j < 4; ++j) {
            int col = w * 64 + j * 16 + lr;
#pragma unroll
            for (int r = 0; r < 4; ++r)
                Ts[rloc + r][col] = (__bf16)acc[j][r];
        }
    }
    __syncthreads();

    // GEMM2: P-stripe = T-stripe @ R  (B-row = Rt[col][:])
    {
        f32x4 acc[4] = {zero, zero, zero, zero};
        for (int kk = 0; kk < 256; kk += 32) {
            bf16x8 af = *(const bf16x8*)&Ts[lr][kk + kofs];
#pragma unroll
            for (int j = 0; j < 4; ++j) {
                int brow = w * 64 + j * 16 + lr;
                bf16x8 bb = *(const bf16x8*)&Rtb[brow * 256 + kk + kofs];
                acc[j] = mfma16(af, bb, acc[j]);
            }
        }
        __bf16* Pbb = Pb + ((size_t)b << 16);
        int row0 = r0 + ((l >> 4) << 2);
#pragma unroll
        for (int j = 0; j < 4; ++j) {
            int col = w * 64 + j * 16 + lr;
#pragma unroll
            for (int r = 0; r < 4; ++r)
                Pbb[(size_t)(row0 + r) * 256 + col] = (__bf16)acc[j][r];
        }
    }
}

// ---------------------------------------------------------------------------
// k_out: out = P @ Qf + shift + Qf  (fused in-LDS transpose of Qf; BN+residual)
// grid 576: b = bid&7 (XCD pin), nt = bid>>3 (72 n-tiles of 32). 512 threads
// (8 waves); wave w owns o in [w*32, w*32+32) x 32 n. B-frags from LDS tile
// Qs[32n][264c] (bf16), staged coalesced from Qf — no global Qft needed.
// ---------------------------------------------------------------------------
__global__ __launch_bounds__(512) void k_out(
    const unsigned short* __restrict__ Pb_us, const float* __restrict__ Qf,
    const float* __restrict__ gamma, const float* __restrict__ beta,
    const float* __restrict__ mean, const float* __restrict__ var_,
    float* __restrict__ out) {
    __shared__ __bf16 Qs[32][264];       // 16.9 KB; pitch 264 keeps 16B frag align
    const __bf16* Pb = (const __bf16*)Pb_us;
    int bid = blockIdx.x;
    int b = bid & 7, nt = bid >> 3;
    int n0 = nt * 32;
    int tid = threadIdx.x, l = tid & 63, w = tid >> 6;     // w in 0..7
    int lr = l & 15, kofs = (l >> 4) * 8;

    // stage Qf[b][:, n0:n0+32] -> Qs[n][c] (transpose + bf16 cvt in LDS)
    const float* src = Qf + (size_t)b * Cc * Nn + n0;
    for (int idx = tid; idx < 2048; idx += 512) {
        int c = idx >> 3, ng = (idx & 7) << 2;
        float4 v = *(const float4*)(src + (size_t)c * Nn + ng);
        Qs[ng + 0][c] = (__bf16)v.x;
        Qs[ng + 1][c] = (__bf16)v.y;
        Qs[ng + 2][c] = (__bf16)v.z;
        Qs[ng + 3][c] = (__bf16)v.w;
    }
    __syncthreads();

    int obase = w * 32;
    const __bf16* A = Pb + ((size_t)b << 16);
    f32x4 zero = {0.f, 0.f, 0.f, 0.f};
    f32x4 acc[2][2];
#pragma unroll
    for (int i = 0; i < 2; ++i)
#pragma unroll
        for (int j = 0; j < 2; ++j) acc[i][j] = zero;

#pragma unroll 2
    for (int kk = 0; kk < 256; kk += 32) {
        bf16x8 af[2], bb[2];
#pragma unroll
        for (int i = 0; i < 2; ++i)
            af[i] = *(const bf16x8*)&A[(size_t)(obase + i * 16 + lr) * 256 + kk + kofs];
#pragma unroll
        for (int j = 0; j < 2; ++j)
            bb[j] = *(const bf16x8*)&Qs[j * 16 + lr][kk + kofs];
#pragma unroll
        for (int i = 0; i < 2; ++i)
#pragma unroll
            for (int j = 0; j < 2; ++j)
                acc[i][j] = mfma16(af[i], bb[j], acc[i][j]);
    }

    const float* Qfb = Qf + (size_t)b * Cc * Nn;
    float* outb = out + (size_t)b * Cc * Nn;
#pragma unroll
    for (int i = 0; i < 2; ++i) {
        int o0 = obase + i * 16 + ((l >> 4) << 2);
#pragma unroll
        for (int r = 0; r < 4; ++r) {
            int o = o0 + r;
            float inv = gamma[o] / sqrtf(var_[o] + EPS);
            float shift = beta[o] - mean[o] * inv;
#pragma unroll
            for (int j = 0; j < 2; ++j) {
                int n = n0 + j * 16 + lr;
                outb[(size_t)o * Nn + n] = acc[i][j][r] + shift + Qfb[(size_t)o * Nn + n];
            }
        }
    }
}

extern "C" void kernel_launch(void* const* d_in, const int* in_sizes, int n_in,
                              void* d_out, int out_size, void* d_ws, size_t ws_size,
                              hipStream_t stream) {
    (void)in_sizes; (void)n_in; (void)out_size; (void)ws_size;
    const float* Qf    = (const float*)d_in[0];
    const float* KVf   = (const float*)d_in[1];
    const float* Wq    = (const float*)d_in[2];
    const float* Wk    = (const float*)d_in[3];
    const float* Wv    = (const float*)d_in[4];
    const float* Wz    = (const float*)d_in[5];
    const float* gamma = (const float*)d_in[6];
    const float* beta  = (const float*)d_in[7];
    const float* mean  = (const float*)d_in[8];
    const float* var_  = (const float*)d_in[9];
    float* out = (float*)d_out;

    char* ws = (char*)d_ws;
    float* Spart        = (float*)ws;                                   // 4*8*256KB = 8 MB
    unsigned short* Lb  = (unsigned short*)(ws + (8u << 20));           // 128 KB
    unsigned short* Rtb = (unsigned short*)(ws + (8u << 20) + (128u << 10));
    unsigned short* Pb  = (unsigned short*)(ws + (8u << 20) + (256u << 10));   // 1 MB

    k_front<<<1024, 256, 0, stream>>>(KVf, Wq, Wk, Wv, Wz, gamma, var_,
                                      Lb, Rtb, Spart);
    k_mid<<<128, 256, 0, stream>>>(Lb, Spart, Rtb, Pb);
    k_out<<<576, 512, 0, stream>>>(Pb, Qf, gamma, beta, mean, var_, out);
}

// Round 13
// 154.711 us; speedup vs baseline: 1.0901x; 1.0901x over previous
//
#include <hip/hip_runtime.h>

#define Bv 8
#define Cc 256
#define Nn 2304
#define EPS 1e-5f

typedef float f32x4 __attribute__((ext_vector_type(4)));
typedef __bf16 bf16x8 __attribute__((ext_vector_type(8)));

static __device__ __forceinline__ f32x4 mfma16(bf16x8 a, bf16x8 b, f32x4 c) {
    return __builtin_amdgcn_mfma_f32_16x16x32_bf16(a, b, c, 0, 0, 0);
}

static __device__ __forceinline__ bf16x8 cvt8(float4 a, float4 b) {
    bf16x8 r;
    r[0] = (__bf16)a.x; r[1] = (__bf16)a.y; r[2] = (__bf16)a.z; r[3] = (__bf16)a.w;
    r[4] = (__bf16)b.x; r[5] = (__bf16)b.y; r[6] = (__bf16)b.z; r[7] = (__bf16)b.w;
    return r;
}

// load 8 contiguous fp32 and convert to bf16x8
static __device__ __forceinline__ bf16x8 load_cvt8(const float* __restrict__ p) {
    return cvt8(*(const float4*)p, *(const float4*)(p + 4));
}

// load 8 fp32 from four partial slabs, sum, convert
static __device__ __forceinline__ bf16x8 load4_add_cvt8(
    const float* __restrict__ p0, const float* __restrict__ p1,
    const float* __restrict__ p2, const float* __restrict__ p3) {
    float4 x0 = *(const float4*)p0, x1 = *(const float4*)(p0 + 4);
    float4 y0 = *(const float4*)p1, y1 = *(const float4*)(p1 + 4);
    float4 z0 = *(const float4*)p2, z1 = *(const float4*)(p2 + 4);
    float4 w0 = *(const float4*)p3, w1 = *(const float4*)(p3 + 4);
    bf16x8 r;
    r[0] = (__bf16)(x0.x + y0.x + z0.x + w0.x);
    r[1] = (__bf16)(x0.y + y0.y + z0.y + w0.y);
    r[2] = (__bf16)(x0.z + y0.z + z0.z + w0.z);
    r[3] = (__bf16)(x0.w + y0.w + z0.w + w0.w);
    r[4] = (__bf16)(x1.x + y1.x + z1.x + w1.x);
    r[5] = (__bf16)(x1.y + y1.y + z1.y + w1.y);
    r[6] = (__bf16)(x1.z + y1.z + z1.z + w1.z);
    r[7] = (__bf16)(x1.w + y1.w + z1.w + w1.w);
    return r;
}

// load 8 fp32 from two partial slabs, sum, convert
static __device__ __forceinline__ bf16x8 load_add_cvt8(const float* __restrict__ p0,
                                                       const float* __restrict__ p1) {
    float4 a0 = *(const float4*)p0;
    float4 a1 = *(const float4*)(p0 + 4);
    float4 b0 = *(const float4*)p1;
    float4 b1 = *(const float4*)(p1 + 4);
    bf16x8 r;
    r[0] = (__bf16)(a0.x + b0.x); r[1] = (__bf16)(a0.y + b0.y);
    r[2] = (__bf16)(a0.z + b0.z); r[3] = (__bf16)(a0.w + b0.w);
    r[4] = (__bf16)(a1.x + b1.x); r[5] = (__bf16)(a1.y + b1.y);
    r[6] = (__bf16)(a1.z + b1.z); r[7] = (__bf16)(a1.w + b1.w);
    return r;
}

// ---------------------------------------------------------------------------
// k_front: two independent jobs:
//   blocks [0,512):    Spart[kc][b] = KVf_chunk @ KVf_chunk^T (4-way split-K,
//                      K-chunk 576, K-step 64, 2-phase reg-prefetch pipeline,
//                      plain stores, b->XCD pinned)
//   blocks [512,1024): L = (1/N)*diag(inv)*(Wz@Wv), Rt = Wq^T@Wk  (bf16 out)
// ---------------------------------------------------------------------------
__global__ __launch_bounds__(256) void k_front(
    const float* __restrict__ KVf,
    const float* __restrict__ Wq, const float* __restrict__ Wk,
    const float* __restrict__ Wv, const float* __restrict__ Wz,
    const float* __restrict__ gamma, const float* __restrict__ var_,
    unsigned short* __restrict__ Lb_us, unsigned short* __restrict__ Rtb_us,
    float* __restrict__ Spart) {
    __shared__ __align__(16) char smem[32768];
    int blk = blockIdx.x, tid = threadIdx.x;

    if (blk < 512) {
        // ---- syrk partial: 64x64 tile, K=576 chunk, K-step 64, pipelined ----
        __bf16 (*As)[72] = (__bf16 (*)[72])smem;                 // 64*72*2 = 9216 B
        __bf16 (*Bs)[72] = (__bf16 (*)[72])(smem + 9216);
        int b = blk & 7;                   // b -> XCD pin
        int tt = (blk >> 3) & 15;
        int kc = blk >> 7;                 // 0..3
        int tr = (tt >> 2) * 64, tc = (tt & 3) * 64;
        int k0 = kc * 576;
        int l = tid & 63, w = tid >> 6;
        int lr = l & 15, kofs = (l >> 4) * 8;
        int row = tid >> 2, c0 = (tid & 3) * 16;
        const float* Ap = KVf + ((size_t)b * Cc + tr + row) * Nn + k0 + c0;
        const float* Bp = KVf + ((size_t)b * Cc + tc + row) * Nn + k0 + c0;
        float4 fa0, fa1, fa2, fa3, fb0, fb1, fb2, fb3;
#define LD_TILE(ks) do { \
        const float* ap_ = Ap + (ks) * 64; \
        const float* bp_ = Bp + (ks) * 64; \
        fa0 = *(const float4*)ap_;         fa1 = *(const float4*)(ap_ + 4); \
        fa2 = *(const float4*)(ap_ + 8);   fa3 = *(const float4*)(ap_ + 12); \
        fb0 = *(const float4*)bp_;         fb1 = *(const float4*)(bp_ + 4); \
        fb2 = *(const float4*)(bp_ + 8);   fb3 = *(const float4*)(bp_ + 12); \
    } while (0)
        f32x4 zero = {0.f, 0.f, 0.f, 0.f};
        f32x4 acc[4] = {zero, zero, zero, zero};
        LD_TILE(0);
        for (int ks = 0; ks < 9; ++ks) {
            *(bf16x8*)&As[row][c0]     = cvt8(fa0, fa1);
            *(bf16x8*)&As[row][c0 + 8] = cvt8(fa2, fa3);
            *(bf16x8*)&Bs[row][c0]     = cvt8(fb0, fb1);
            *(bf16x8*)&Bs[row][c0 + 8] = cvt8(fb2, fb3);
            __syncthreads();
            if (ks < 8) LD_TILE(ks + 1);   // prefetch next tile into regs
#pragma unroll
            for (int kk = 0; kk < 64; kk += 32) {
                bf16x8 af = *(const bf16x8*)&As[w * 16 + lr][kk + kofs];
#pragma unroll
                for (int j = 0; j < 4; ++j) {
                    bf16x8 bb = *(const bf16x8*)&Bs[j * 16 + lr][kk + kofs];
                    acc[j] = mfma16(af, bb, acc[j]);
                }
            }
            __syncthreads();
        }
#undef LD_TILE
        float* Sp = Spart + ((size_t)kc * Bv + b) * 65536;
        int row0 = tr + w * 16 + ((l >> 4) << 2);
#pragma unroll
        for (int j = 0; j < 4; ++j) {
            int col = tc + j * 16 + lr;
#pragma unroll
            for (int r = 0; r < 4; ++r)
                Sp[(size_t)(row0 + r) * 256 + col] = acc[j][r];
        }
    } else {
        // ---- weight GEMMs (fp32 LDS dot) ----
        float* bufA = (float*)smem;
        float* bufB = bufA + 4096;
        __bf16* Lb  = (__bf16*)Lb_us;
        __bf16* Rtb = (__bf16*)Rtb_us;
        int wblk = blk - 512;
        bool isL = (wblk < 256);
        int t = isL ? wblk : wblk - 256;
        int tr = (t >> 4) * 16, tc = (t & 15) * 16;
        if (isL) {
            for (int idx = tid; idx < 4096; idx += 256) {
                int r = idx >> 8, m = idx & 255;
                bufA[idx] = Wz[(tr + r) * 256 + m];          // [16][256] rows of Wz
            }
            for (int idx = tid; idx < 4096; idx += 256) {
                int m = idx >> 4, j = idx & 15;
                bufB[idx] = Wv[m * 256 + tc + j];            // [256][16] cols of Wv
            }
        } else {
            for (int idx = tid; idx < 4096; idx += 256) {
                int o = idx >> 4, j = idx & 15;
                bufA[idx] = Wq[o * 256 + tr + j];            // [256][16] cols of Wq
                bufB[idx] = Wk[o * 256 + tc + j];            // [256][16] cols of Wk
            }
        }
        __syncthreads();
        int oo = tid >> 4, cc = tid & 15;
        float sum = 0.f;
        if (isL) {
#pragma unroll 8
            for (int m = 0; m < 256; ++m) sum += bufA[oo * 256 + m] * bufB[m * 16 + cc];
            int o = tr + oo;
            float inv = gamma[o] / sqrtf(var_[o] + EPS);
            Lb[o * 256 + tc + cc] = (__bf16)(inv * sum * (1.0f / (float)Nn));
        } else {
#pragma unroll 8
            for (int o = 0; o < 256; ++o) sum += bufA[o * 16 + oo] * bufB[o * 16 + cc];
            Rtb[(tr + oo) * 256 + tc + cc] = (__bf16)sum;
        }
    }
}

// ---------------------------------------------------------------------------
// k_mid1: Tpart[kc][b] = L[rows] @ (S0+S1+S2+S3)[b]  (NT via S symmetry,
// 2-way split-K). grid 256 = 2 kc x 16 tiles(64x64) x 8 b (b->XCD pin).
// ---------------------------------------------------------------------------
__global__ __launch_bounds__(256) void k_mid1(
    const unsigned short* __restrict__ Lb_us, const float* __restrict__ Spart,
    float* __restrict__ Tpart) {
    const __bf16* Lb = (const __bf16*)Lb_us;
    int blk = blockIdx.x;
    int b = blk & 7;
    int t = (blk >> 3) & 15;
    int kc = blk >> 7;
    int tr = (t >> 2) * 64, tc = (t & 3) * 64;
    int k0 = kc * 128;
    int tid = threadIdx.x, l = tid & 63, w = tid >> 6;
    int lr = l & 15, kofs = (l >> 4) * 8;
    const float* S0 = Spart + (size_t)(0 * Bv + b) * 65536;
    const float* S1 = Spart + (size_t)(1 * Bv + b) * 65536;
    const float* S2 = Spart + (size_t)(2 * Bv + b) * 65536;
    const float* S3 = Spart + (size_t)(3 * Bv + b) * 65536;
    f32x4 zero = {0.f, 0.f, 0.f, 0.f};
    f32x4 acc[4] = {zero, zero, zero, zero};
    int arow = tr + w * 16 + lr;
    for (int kk = 0; kk < 128; kk += 32) {
        bf16x8 af = *(const bf16x8*)&Lb[arow * 256 + k0 + kk + kofs];
#pragma unroll
        for (int j = 0; j < 4; ++j) {
            size_t boff = (size_t)(tc + j * 16 + lr) * 256 + k0 + kk + kofs;
            bf16x8 bb = load4_add_cvt8(S0 + boff, S1 + boff, S2 + boff, S3 + boff);
            acc[j] = mfma16(af, bb, acc[j]);
        }
    }
    float* Tp = Tpart + ((size_t)kc * Bv + b) * 65536;
    int row0 = tr + w * 16 + ((l >> 4) << 2);
#pragma unroll
    for (int j = 0; j < 4; ++j) {
        int col = tc + j * 16 + lr;
#pragma unroll
        for (int r = 0; r < 4; ++r)
            Tp[(size_t)(row0 + r) * 256 + col] = acc[j][r];
    }
}

// ---------------------------------------------------------------------------
// k_mid2: P[b] = (T0+T1)[b] @ R  (NT with Rt). grid 128 = 16 tiles x 8 b.
// ---------------------------------------------------------------------------
__global__ __launch_bounds__(256) void k_mid2(
    const float* __restrict__ Tpart, const unsigned short* __restrict__ Rtb_us,
    unsigned short* __restrict__ Pb_us) {
    const __bf16* Rtb = (const __bf16*)Rtb_us;
    __bf16* Pb = (__bf16*)Pb_us;
    int blk = blockIdx.x;
    int b = blk & 7;
    int t = blk >> 3;
    int tr = (t >> 2) * 64, tc = (t & 3) * 64;
    int tid = threadIdx.x, l = tid & 63, w = tid >> 6;
    int lr = l & 15, kofs = (l >> 4) * 8;
    const float* T0 = Tpart + (size_t)b * 65536;
    const float* T1 = Tpart + (size_t)(Bv + b) * 65536;
    f32x4 zero = {0.f, 0.f, 0.f, 0.f};
    f32x4 acc[4] = {zero, zero, zero, zero};
    int arow = tr + w * 16 + lr;
    for (int kk = 0; kk < 256; kk += 32) {
        bf16x8 af = load_add_cvt8(&T0[(size_t)arow * 256 + kk + kofs],
                                  &T1[(size_t)arow * 256 + kk + kofs]);
#pragma unroll
        for (int j = 0; j < 4; ++j) {
            int brow = tc + j * 16 + lr;
            bf16x8 bb = *(const bf16x8*)&Rtb[brow * 256 + kk + kofs];
            acc[j] = mfma16(af, bb, acc[j]);
        }
    }
    __bf16* Pbb = Pb + ((size_t)b << 16);
    int row0 = tr + w * 16 + ((l >> 4) << 2);
#pragma unroll
    for (int j = 0; j < 4; ++j) {
        int col = tc + j * 16 + lr;
#pragma unroll
        for (int r = 0; r < 4; ++r)
            Pbb[(size_t)(row0 + r) * 256 + col] = (__bf16)acc[j][r];
    }
}

// ---------------------------------------------------------------------------
// k_out: out = P @ Qf + shift + Qf  (fused in-LDS transpose of Qf; BN+residual)
// grid 288: b = bid&7 (XCD pin), nt = bid>>3 (36 n-tiles of 64). 512 threads
// (8 waves); wave w owns o in [w*32, w*32+32) x 64 n. B-frags from LDS tile
// Qs[64n][264c] (bf16), staged coalesced from Qf — no global Qft needed.
// ---------------------------------------------------------------------------
__global__ __launch_bounds__(512) void k_out(
    const unsigned short* __restrict__ Pb_us, const float* __restrict__ Qf,
    const float* __restrict__ gamma, const float* __restrict__ beta,
    const float* __restrict__ mean, const float* __restrict__ var_,
    float* __restrict__ out) {
    __shared__ __bf16 Qs[64][264];       // 33,792 B; pitch 264 keeps 16B frag align
    const __bf16* Pb = (const __bf16*)Pb_us;
    int bid = blockIdx.x;
    int b = bid & 7, nt = bid >> 3;
    int n0 = nt * 64;
    int tid = threadIdx.x, l = tid & 63, w = tid >> 6;     // w in 0..7
    int lr = l & 15, kofs = (l >> 4) * 8;

    // stage Qf[b][:, n0:n0+64] -> Qs[n][c] (transpose + bf16 cvt in LDS)
    const float* src = Qf + (size_t)b * Cc * Nn + n0;
    for (int idx = tid; idx < 4096; idx += 512) {
        int c = idx >> 4, ng = (idx & 15) << 2;
        float4 v = *(const float4*)(src + (size_t)c * Nn + ng);
        Qs[ng + 0][c] = (__bf16)v.x;
        Qs[ng + 1][c] = (__bf16)v.y;
        Qs[ng + 2][c] = (__bf16)v.z;
        Qs[ng + 3][c] = (__bf16)v.w;
    }
    __syncthreads();

    int obase = w * 32;
    const __bf16* A = Pb + ((size_t)b << 16);
    f32x4 zero = {0.f, 0.f, 0.f, 0.f};
    f32x4 acc[2][4];
#pragma unroll
    for (int i = 0; i < 2; ++i)
#pragma unroll
        for (int j = 0; j < 4; ++j) acc[i][j] = zero;

    for (int kk = 0; kk < 256; kk += 32) {
        bf16x8 af[2], bb[4];
#pragma unroll
        for (int i = 0; i < 2; ++i)
            af[i] = *(const bf16x8*)&A[(size_t)(obase + i * 16 + lr) * 256 + kk + kofs];
#pragma unroll
        for (int j = 0; j < 4; ++j)
            bb[j] = *(const bf16x8*)&Qs[j * 16 + lr][kk + kofs];
#pragma unroll
        for (int i = 0; i < 2; ++i)
#pragma unroll
            for (int j = 0; j < 4; ++j)
                acc[i][j] = mfma16(af[i], bb[j], acc[i][j]);
    }

    const float* Qfb = Qf + (size_t)b * Cc * Nn;
    float* outb = out + (size_t)b * Cc * Nn;
#pragma unroll
    for (int i = 0; i < 2; ++i) {
        int o0 = obase + i * 16 + ((l >> 4) << 2);
#pragma unroll
        for (int r = 0; r < 4; ++r) {
            int o = o0 + r;
            float inv = gamma[o] / sqrtf(var_[o] + EPS);
            float shift = beta[o] - mean[o] * inv;
#pragma unroll
            for (int j = 0; j < 4; ++j) {
                int n = n0 + j * 16 + lr;
                outb[(size_t)o * Nn + n] = acc[i][j][r] + shift + Qfb[(size_t)o * Nn + n];
            }
        }
    }
}

extern "C" void kernel_launch(void* const* d_in, const int* in_sizes, int n_in,
                              void* d_out, int out_size, void* d_ws, size_t ws_size,
                              hipStream_t stream) {
    (void)in_sizes; (void)n_in; (void)out_size; (void)ws_size;
    const float* Qf    = (const float*)d_in[0];
    const float* KVf   = (const float*)d_in[1];
    const float* Wq    = (const float*)d_in[2];
    const float* Wk    = (const float*)d_in[3];
    const float* Wv    = (const float*)d_in[4];
    const float* Wz    = (const float*)d_in[5];
    const float* gamma = (const float*)d_in[6];
    const float* beta  = (const float*)d_in[7];
    const float* mean  = (const float*)d_in[8];
    const float* var_  = (const float*)d_in[9];
    float* out = (float*)d_out;

    char* ws = (char*)d_ws;
    float* Spart        = (float*)ws;                                   // 4*8*256KB = 8 MB
    float* Tpart        = (float*)(ws + (8u << 20));                    // 2*8*256KB = 4 MB
    unsigned short* Lb  = (unsigned short*)(ws + (12u << 20));          // 128 KB
    unsigned short* Rtb = (unsigned short*)(ws + (12u << 20) + (128u << 10));
    unsigned short* Pb  = (unsigned short*)(ws + (12u << 20) + (256u << 10));  // 1 MB

    k_front<<<1024, 256, 0, stream>>>(KVf, Wq, Wk, Wv, Wz, gamma, var_,
                                      Lb, Rtb, Spart);
    k_mid1<<<256, 256, 0, stream>>>(Lb, Spart, Tpart);
    k_mid2<<<128, 256, 0, stream>>>(Tpart, Rtb, Pb);
    k_out<<<288, 512, 0, stream>>>(Pb, Qf, gamma, beta, mean, var_, out);
}